// Round 10
// baseline (107.140 us; speedup 1.0000x reference)
//
#include <hip/hip_runtime.h>

// AnnularDilatedKNN: B=4, N=4096, C=64, SAMPLE=16, DILATED_RATE=2, r^2=256.
// Round 13: RESUBMIT of round-12 (round-9 bench was an infra failure:
// "MI355X container failed twice" -- no compile/test ran; no evidence
// against this kernel; all constructs individually harness-passed).
//  - Block = 4 consecutive CELL-SORTED points -> the 4 waves scan
//    ~identical candidate ranges; wave 0 warms L1, waves 1-3 hit L1;
//    adjacent blocks on a CU reuse again. Gather feat rows L1-hot.
//  - Own point from Sb[q0+wave] (sq recomputed bit-identically),
//    jof[wave]=bitcast(pr.w), gather ob=jof*16+k (round-3-passed).
//  - Dual-chunk guarded loop + hoisted bounds (round-11-passed).
//  - K1 verbatim round-10 (passed).
//  Hit test bit-identical: sq=(x*x+y*y)+z*z, dot=(xi*xj+yi*yj)+zi*zj,
//  d2=(sqi+sqj)-2*dot, contract off. Clamped dup rows harmless (mask OR
//  idempotent). No speculative loads.

#define BB 4
#define NN 4096
#define KK 16
#define PLANE (NN * KK)   // 65536
#define NC 20
#define NCELL2 (NC * NC)  // 400

__device__ __forceinline__ int cell1d(float v)
{
    int c = (int)floorf((v + 160.0f) * 0.0625f);
    c = c < 0 ? 0 : c;
    return c > (NC - 1) ? (NC - 1) : c;
}

// ---------- K1: per-batch 2D histogram -> scan -> scatter (1 block/batch) ----------
// 1024 threads; thread t owns points 4t..4t+3 of its batch.
__global__ __launch_bounds__(1024)
void preprocess(const float* __restrict__ xyz, float4* __restrict__ SP,
                int* __restrict__ CS)
{
#pragma clang fp contract(off)
    __shared__ int hist[NCELL2];

    const int b = blockIdx.x;
    const int t = threadIdx.x;
    const float4* xb4 = (const float4*)(xyz + (size_t)b * NN * 3);

    if (t < NCELL2) hist[t] = 0;
    __syncthreads();

    // load 4 consecutive points (3 coalesced float4), keep in registers
    const float4 v0 = xb4[3 * t];
    const float4 v1 = xb4[3 * t + 1];
    const float4 v2 = xb4[3 * t + 2];
    const float px0 = v0.x, py0 = v0.y, pz0 = v0.z;
    const float px1 = v0.w, py1 = v1.x, pz1 = v1.y;
    const float px2 = v1.z, py2 = v1.w, pz2 = v2.x;
    const float px3 = v2.y, py3 = v2.z, pz3 = v2.w;
    const int c0 = cell1d(py0) * NC + cell1d(px0);
    const int c1 = cell1d(py1) * NC + cell1d(px1);
    const int c2 = cell1d(py2) * NC + cell1d(px2);
    const int c3 = cell1d(py3) * NC + cell1d(px3);
    atomicAdd(&hist[c0], 1);
    atomicAdd(&hist[c1], 1);
    atomicAdd(&hist[c2], 1);
    atomicAdd(&hist[c3], 1);
    __syncthreads();

    // wave 0 scans the 400 cells (7 cells per lane, statically indexed)
    if (t < 64) {
        const int base = t * 7;
        int loc0 = 0, loc1 = 0, loc2 = 0, loc3 = 0, loc4 = 0, loc5 = 0, loc6 = 0;
        if (base + 0 < NCELL2) loc0 = hist[base + 0];
        if (base + 1 < NCELL2) loc1 = hist[base + 1];
        if (base + 2 < NCELL2) loc2 = hist[base + 2];
        if (base + 3 < NCELL2) loc3 = hist[base + 3];
        if (base + 4 < NCELL2) loc4 = hist[base + 4];
        if (base + 5 < NCELL2) loc5 = hist[base + 5];
        if (base + 6 < NCELL2) loc6 = hist[base + 6];
        const int s = loc0 + loc1 + loc2 + loc3 + loc4 + loc5 + loc6;
        int x = s;
#pragma unroll
        for (int off = 1; off < 64; off <<= 1) {
            const int u = __shfl_up(x, off, 64);
            if (t >= off) x += u;
        }
        int acc = x - s;                       // exclusive prefix
        int* cs = CS + b * (NCELL2 + 1);
        if (base + 0 < NCELL2) { cs[base + 0] = acc; hist[base + 0] = acc; acc += loc0; }
        if (base + 1 < NCELL2) { cs[base + 1] = acc; hist[base + 1] = acc; acc += loc1; }
        if (base + 2 < NCELL2) { cs[base + 2] = acc; hist[base + 2] = acc; acc += loc2; }
        if (base + 3 < NCELL2) { cs[base + 3] = acc; hist[base + 3] = acc; acc += loc3; }
        if (base + 4 < NCELL2) { cs[base + 4] = acc; hist[base + 4] = acc; acc += loc4; }
        if (base + 5 < NCELL2) { cs[base + 5] = acc; hist[base + 5] = acc; acc += loc5; }
        if (base + 6 < NCELL2) { cs[base + 6] = acc; hist[base + 6] = acc; acc += loc6; }
        if (t == 0) cs[NCELL2] = NN;
    }
    __syncthreads();

    // scatter from registers; SP.w carries original index
    {
        int slot;
        slot = atomicAdd(&hist[c0], 1);
        SP[(b << 12) + slot] = make_float4(px0, py0, pz0, __int_as_float(4 * t + 0));
        slot = atomicAdd(&hist[c1], 1);
        SP[(b << 12) + slot] = make_float4(px1, py1, pz1, __int_as_float(4 * t + 1));
        slot = atomicAdd(&hist[c2], 1);
        SP[(b << 12) + slot] = make_float4(px2, py2, pz2, __int_as_float(4 * t + 2));
        slot = atomicAdd(&hist[c3], 1);
        SP[(b << 12) + slot] = make_float4(px3, py3, pz3, __int_as_float(4 * t + 3));
    }
}

// ---------- K2: fused grid ball query + gather, sorted point order ----------
// grid: 4096 blocks x 256 threads; block handles 4 consecutive SORTED points,
// wave w queries sorted point q0+w (waves share ~identical candidate ranges).
__global__ __launch_bounds__(256, 8)
void query_gather(const float* __restrict__ xyz, const float4* __restrict__ SP,
                  const int* __restrict__ CS, const float* __restrict__ feat,
                  float* __restrict__ out)
{
#pragma clang fp contract(off)
    __shared__ unsigned int mask[4][128];   // 4096-bit hit mask per point
    __shared__ int sids[4 * KK];
    __shared__ int jof[4];                  // original index of each point

    const int beta = blockIdx.x;
    const int b    = beta >> 10;
    const int q0   = (beta & 1023) * 4;     // first sorted point of block
    const int t    = threadIdx.x;
    const int lane = t & 63;
    const int wave = t >> 6;

    const float* xb   = xyz + (size_t)b * NN * 3;
    const float4* Sb  = SP + (b << 12);
    const int*    csb = CS + b * (NCELL2 + 1);

    // own point (sorted order); sq recomputed bit-identically
    const float4 pr  = Sb[q0 + wave];
    const float  pix = pr.x, piy = pr.y, piz = pr.z;
    const float  sqi = (pix * pix + piy * piy) + piz * piz;
    if (lane == 0) jof[wave] = __float_as_int(pr.w);

    // zero own mask (own-wave use only -> no barrier needed before query)
    unsigned int* m = mask[wave];
    m[2 * lane]     = 0u;
    m[2 * lane + 1] = 0u;

    // ---- query: 3 y-rows, bounds hoisted to named scalars, dual-chunk loop ----
    {
        const int cx = cell1d(pix), cy = cell1d(piy);
        const int xlo = cx > 0 ? cx - 1 : 0;
        const int xhi = cx < NC - 1 ? cx + 1 : NC - 1;
        const int yA = (cy - 1) < 0 ? 0 : cy - 1;            // dup rows harmless (OR)
        const int yC = (cy + 1) > NC - 1 ? NC - 1 : cy + 1;

        // all 6 bounds issued up-front, independent wave-uniform loads
        const int sA = csb[yA * NC + xlo], eA = csb[yA * NC + xhi + 1];
        const int sB = csb[cy * NC + xlo], eB = csb[cy * NC + xhi + 1];
        const int sC = csb[yC * NC + xlo], eC = csb[yC * NC + xhi + 1];

#pragma unroll
        for (int rr = 0; rr < 3; ++rr) {
            const int s = rr == 0 ? sA : (rr == 1 ? sB : sC);
            const int e = rr == 0 ? eA : (rr == 1 ? eB : eC);
            for (int v = s + lane; v < e; v += 128) {         // 2 chunks/iter
                const float4 a = Sb[v];
                const int v2   = v + 64;
                const bool h2  = v2 < e;
                float4 c2;
                if (h2) c2 = Sb[v2];                          // guarded, no spec
                const float sqa = (a.x * a.x + a.y * a.y) + a.z * a.z;
                const float da  = (pix * a.x + piy * a.y) + piz * a.z;
                const float d2a = (sqi + sqa) - 2.0f * da;
                if (d2a < 256.0f) {
                    const int j = __float_as_int(a.w);
                    atomicOr(&m[j >> 5], 1u << (j & 31));
                }
                if (h2) {
                    const float sqc = (c2.x * c2.x + c2.y * c2.y) + c2.z * c2.z;
                    const float dc  = (pix * c2.x + piy * c2.y) + piz * c2.z;
                    const float d2c = (sqi + sqc) - 2.0f * dc;
                    if (d2c < 256.0f) {
                        const int j = __float_as_int(c2.w);
                        atomicOr(&m[j >> 5], 1u << (j & 31));
                    }
                }
            }
        }
    }

    // ---- rank extraction: lane l owns indices [64l, 64l+64) (own mask) ----
    {
        const unsigned int lo  = m[2 * lane];
        const unsigned int hiw = m[2 * lane + 1];
        const unsigned long long w = ((unsigned long long)hiw << 32) | lo;
        const int c = __popcll(w);
        int x = c;                                  // inclusive scan of counts
#pragma unroll
        for (int off = 1; off < 64; off <<= 1) {
            const int u = __shfl_up(x, off, 64);
            if (lane >= off) x += u;
        }
        const int cnt  = __shfl(x, 63, 64);         // total hits
        const int base = x - c;                     // hits before this lane

        int fj = 0x7fffffff;                        // global first hit
        if (w) fj = (lane << 6) + __builtin_ctzll(w);
        for (int off = 32; off; off >>= 1) {
            const int o = __shfl_xor(fj, off, 64);
            fj = fj < o ? fj : o;
        }

        int* row = sids + wave * KK;
        if (w && base <= 30 && base + c > 16) {     // lane covers ranks 16..30?
            unsigned long long ww = w;
            int r = base;
            while (ww) {
                if (r > 30) break;
                if (r >= 16) row[r - 15] = (lane << 6) + __builtin_ctzll(ww);
                ww &= ww - 1;
                ++r;
            }
        }
        const int hi = (cnt < 31 ? cnt : 31) - 16;
        if (lane < KK && (lane == 0 || lane > hi)) row[lane] = fj;
    }
    __syncthreads();

    // ---- gather: thread t -> (point rowi>>4, k rowi&15), channel quarter t>>6 ----
    const int rowi = t & 63;
    const int part = t >> 6;
    const int id   = sids[rowi];
    const int ob   = jof[rowi >> 4] * KK + (rowi & 15);

    if (part == 0) {                                // dilated_xyz [B,3,N,K]
        float* o0 = out + (size_t)b * 3 * PLANE + ob;
        o0[0]         = xb[3 * id];
        o0[PLANE]     = xb[3 * id + 1];
        o0[2 * PLANE] = xb[3 * id + 2];
    }

    // dilated_feature [B,64,N,K], channels [16*part, 16*part+16)
    const float4* frow = reinterpret_cast<const float4*>(feat + ((size_t)(b << 12) + id) * 64) + part * 4;
    float* o1 = out + (size_t)BB * 3 * PLANE + (size_t)b * 64 * PLANE
                    + (size_t)(part * 16) * PLANE + ob;
#pragma unroll
    for (int q = 0; q < 4; ++q) {
        const float4 v = frow[q];
        float* oc = o1 + (size_t)(4 * q) * PLANE;
        oc[0]         = v.x;
        oc[PLANE]     = v.y;
        oc[2 * PLANE] = v.z;
        oc[3 * PLANE] = v.w;
    }
}

extern "C" void kernel_launch(void* const* d_in, const int* in_sizes, int n_in,
                              void* d_out, int out_size, void* d_ws, size_t ws_size,
                              hipStream_t stream) {
    const float* xyz  = (const float*)d_in[0];
    const float* feat = (const float*)d_in[1];
    float* out = (float*)d_out;

    char* ws = (char*)d_ws;
    float4* SP = (float4*)(ws);                // 16384*16 = 262144
    int*    CS = (int*)   (ws + 262144);       // 4*401*4 = 6416 (total ~263 KB)

    preprocess  <<<BB,          1024, 0, stream>>>(xyz, SP, CS);
    query_gather<<<BB * NN / 4, 256,  0, stream>>>(xyz, SP, CS, feat, out);
}

// Round 12
// 106.983 us; speedup vs baseline: 1.0015x; 1.0015x over previous
//
#include <hip/hip_runtime.h>

// AnnularDilatedKNN: B=4, N=4096, C=64, SAMPLE=16, DILATED_RATE=2, r^2=256.
// Round 15: round-8 kernel (PASSED twice, 102.2us) + ONE audited delta.
//  Crash pattern (r7/r8/r14): every query-LOOP restructure crashed; the
//  simple per-row "for (v=s+lane; v<e; v+=stride)" shape passed 4x. So the
//  loop stays BYTE-IDENTICAL to round-8's dual-chunk version. Only change:
//  - K1 scatter stores sq in SP.w (bit-identical (x*x+y*y)+z*z, contract
//    off -- same hit set) and original index in parallel SI[] (16KB,
//    L1-resident). K2 uses a.w as sqj (drops the 5-op sqj recompute from
//    EVERY candidate) and loads SI[v] ONLY inside the hit branch (~7%).
//  K1 base structure: round-10 (passed 3x). K2 loop/rank/gather: round-8
//  verbatim. Hit test bit-identical: dot=(xi*xj+yi*yj)+zi*zj,
//  d2=(sqi+sqj)-2*dot, contract off. Clamped dup rows harmless (mask OR
//  idempotent). Guarded loads only, no speculation.

#define BB 4
#define NN 4096
#define KK 16
#define PLANE (NN * KK)   // 65536
#define NC 20
#define NCELL2 (NC * NC)  // 400

__device__ __forceinline__ int cell1d(float v)
{
    int c = (int)floorf((v + 160.0f) * 0.0625f);
    c = c < 0 ? 0 : c;
    return c > (NC - 1) ? (NC - 1) : c;
}

// ---------- K1: per-batch 2D histogram -> scan -> scatter (1 block/batch) ----------
// 1024 threads; thread t owns points 4t..4t+3 of its batch.
__global__ __launch_bounds__(1024)
void preprocess(const float* __restrict__ xyz, float4* __restrict__ SP,
                int* __restrict__ SI, int* __restrict__ CS)
{
#pragma clang fp contract(off)
    __shared__ int hist[NCELL2];

    const int b = blockIdx.x;
    const int t = threadIdx.x;
    const float4* xb4 = (const float4*)(xyz + (size_t)b * NN * 3);

    if (t < NCELL2) hist[t] = 0;
    __syncthreads();

    // load 4 consecutive points (3 coalesced float4), keep in registers
    const float4 v0 = xb4[3 * t];
    const float4 v1 = xb4[3 * t + 1];
    const float4 v2 = xb4[3 * t + 2];
    const float px0 = v0.x, py0 = v0.y, pz0 = v0.z;
    const float px1 = v0.w, py1 = v1.x, pz1 = v1.y;
    const float px2 = v1.z, py2 = v1.w, pz2 = v2.x;
    const float px3 = v2.y, py3 = v2.z, pz3 = v2.w;
    const int c0 = cell1d(py0) * NC + cell1d(px0);
    const int c1 = cell1d(py1) * NC + cell1d(px1);
    const int c2 = cell1d(py2) * NC + cell1d(px2);
    const int c3 = cell1d(py3) * NC + cell1d(px3);
    atomicAdd(&hist[c0], 1);
    atomicAdd(&hist[c1], 1);
    atomicAdd(&hist[c2], 1);
    atomicAdd(&hist[c3], 1);
    __syncthreads();

    // wave 0 scans the 400 cells (7 cells per lane, statically indexed)
    if (t < 64) {
        const int base = t * 7;
        int loc0 = 0, loc1 = 0, loc2 = 0, loc3 = 0, loc4 = 0, loc5 = 0, loc6 = 0;
        if (base + 0 < NCELL2) loc0 = hist[base + 0];
        if (base + 1 < NCELL2) loc1 = hist[base + 1];
        if (base + 2 < NCELL2) loc2 = hist[base + 2];
        if (base + 3 < NCELL2) loc3 = hist[base + 3];
        if (base + 4 < NCELL2) loc4 = hist[base + 4];
        if (base + 5 < NCELL2) loc5 = hist[base + 5];
        if (base + 6 < NCELL2) loc6 = hist[base + 6];
        const int s = loc0 + loc1 + loc2 + loc3 + loc4 + loc5 + loc6;
        int x = s;
#pragma unroll
        for (int off = 1; off < 64; off <<= 1) {
            const int u = __shfl_up(x, off, 64);
            if (t >= off) x += u;
        }
        int acc = x - s;                       // exclusive prefix
        int* cs = CS + b * (NCELL2 + 1);
        if (base + 0 < NCELL2) { cs[base + 0] = acc; hist[base + 0] = acc; acc += loc0; }
        if (base + 1 < NCELL2) { cs[base + 1] = acc; hist[base + 1] = acc; acc += loc1; }
        if (base + 2 < NCELL2) { cs[base + 2] = acc; hist[base + 2] = acc; acc += loc2; }
        if (base + 3 < NCELL2) { cs[base + 3] = acc; hist[base + 3] = acc; acc += loc3; }
        if (base + 4 < NCELL2) { cs[base + 4] = acc; hist[base + 4] = acc; acc += loc4; }
        if (base + 5 < NCELL2) { cs[base + 5] = acc; hist[base + 5] = acc; acc += loc5; }
        if (base + 6 < NCELL2) { cs[base + 6] = acc; hist[base + 6] = acc; acc += loc6; }
        if (t == 0) cs[NCELL2] = NN;
    }
    __syncthreads();

    // scatter from registers; SP.w = sq (bit-identical), SI = original index
    {
        int slot;
        slot = atomicAdd(&hist[c0], 1);
        SP[(b << 12) + slot] = make_float4(px0, py0, pz0, (px0 * px0 + py0 * py0) + pz0 * pz0);
        SI[(b << 12) + slot] = 4 * t + 0;
        slot = atomicAdd(&hist[c1], 1);
        SP[(b << 12) + slot] = make_float4(px1, py1, pz1, (px1 * px1 + py1 * py1) + pz1 * pz1);
        SI[(b << 12) + slot] = 4 * t + 1;
        slot = atomicAdd(&hist[c2], 1);
        SP[(b << 12) + slot] = make_float4(px2, py2, pz2, (px2 * px2 + py2 * py2) + pz2 * pz2);
        SI[(b << 12) + slot] = 4 * t + 2;
        slot = atomicAdd(&hist[c3], 1);
        SP[(b << 12) + slot] = make_float4(px3, py3, pz3, (px3 * px3 + py3 * py3) + pz3 * pz3);
        SI[(b << 12) + slot] = 4 * t + 3;
    }
}

// ---------- K2: fused grid ball query + gather ----------
// grid: 4096 blocks x 256 threads; block handles 4 consecutive points
// (ORIGINAL order), wave w queries point p0+w via 3 contiguous runs.
__global__ __launch_bounds__(256, 8)
void query_gather(const float* __restrict__ xyz, const float4* __restrict__ SP,
                  const int* __restrict__ SI, const int* __restrict__ CS,
                  const float* __restrict__ feat, float* __restrict__ out)
{
#pragma clang fp contract(off)
    __shared__ unsigned int mask[4][128];   // 4096-bit hit mask per point
    __shared__ int sids[4 * KK];

    const int beta = blockIdx.x;
    const int b    = beta >> 10;
    const int p0   = (beta & 1023) * 4;
    const int t    = threadIdx.x;
    const int lane = t & 63;
    const int wave = t >> 6;

    const float* xb   = xyz + (size_t)b * NN * 3;
    const float4* Sb  = SP + (b << 12);
    const int*    Ib  = SI + (b << 12);
    const int*    csb = CS + b * (NCELL2 + 1);

    // own point (original order): wave-uniform scalar loads, sq bit-identical
    const int   ip  = p0 + wave;
    const float pix = xb[3 * ip];
    const float piy = xb[3 * ip + 1];
    const float piz = xb[3 * ip + 2];
    const float sqi = (pix * pix + piy * piy) + piz * piz;

    // zero own mask (own-wave use only -> no barrier needed before query)
    unsigned int* m = mask[wave];
    m[2 * lane]     = 0u;
    m[2 * lane + 1] = 0u;

    // ---- query: 3 y-rows, bounds hoisted to named scalars, dual-chunk loop ----
    {
        const int cx = cell1d(pix), cy = cell1d(piy);
        const int xlo = cx > 0 ? cx - 1 : 0;
        const int xhi = cx < NC - 1 ? cx + 1 : NC - 1;
        const int yA = (cy - 1) < 0 ? 0 : cy - 1;            // dup rows harmless (OR)
        const int yC = (cy + 1) > NC - 1 ? NC - 1 : cy + 1;

        // all 6 bounds issued up-front, independent wave-uniform loads
        const int sA = csb[yA * NC + xlo], eA = csb[yA * NC + xhi + 1];
        const int sB = csb[cy * NC + xlo], eB = csb[cy * NC + xhi + 1];
        const int sC = csb[yC * NC + xlo], eC = csb[yC * NC + xhi + 1];

#pragma unroll
        for (int rr = 0; rr < 3; ++rr) {
            const int s = rr == 0 ? sA : (rr == 1 ? sB : sC);
            const int e = rr == 0 ? eA : (rr == 1 ? eB : eC);
            for (int v = s + lane; v < e; v += 128) {         // 2 chunks/iter
                const float4 a = Sb[v];
                const int v2   = v + 64;
                const bool h2  = v2 < e;
                float4 c2;
                if (h2) c2 = Sb[v2];                          // guarded, no spec
                const float da  = (pix * a.x + piy * a.y) + piz * a.z;
                const float d2a = (sqi + a.w) - 2.0f * da;    // a.w = sqj (K1)
                if (d2a < 256.0f) {
                    const int j = Ib[v];                      // hit-only load
                    atomicOr(&m[j >> 5], 1u << (j & 31));
                }
                if (h2) {
                    const float dc  = (pix * c2.x + piy * c2.y) + piz * c2.z;
                    const float d2c = (sqi + c2.w) - 2.0f * dc;
                    if (d2c < 256.0f) {
                        const int j = Ib[v2];                 // hit-only load
                        atomicOr(&m[j >> 5], 1u << (j & 31));
                    }
                }
            }
        }
    }

    // ---- rank extraction: lane l owns indices [64l, 64l+64) (own mask) ----
    {
        const unsigned int lo  = m[2 * lane];
        const unsigned int hiw = m[2 * lane + 1];
        const unsigned long long w = ((unsigned long long)hiw << 32) | lo;
        const int c = __popcll(w);
        int x = c;                                  // inclusive scan of counts
#pragma unroll
        for (int off = 1; off < 64; off <<= 1) {
            const int u = __shfl_up(x, off, 64);
            if (lane >= off) x += u;
        }
        const int cnt  = __shfl(x, 63, 64);         // total hits
        const int base = x - c;                     // hits before this lane

        int fj = 0x7fffffff;                        // global first hit
        if (w) fj = (lane << 6) + __builtin_ctzll(w);
        for (int off = 32; off; off >>= 1) {
            const int o = __shfl_xor(fj, off, 64);
            fj = fj < o ? fj : o;
        }

        int* row = sids + wave * KK;
        if (w && base <= 30 && base + c > 16) {     // lane covers ranks 16..30?
            unsigned long long ww = w;
            int r = base;
            while (ww) {
                if (r > 30) break;
                if (r >= 16) row[r - 15] = (lane << 6) + __builtin_ctzll(ww);
                ww &= ww - 1;
                ++r;
            }
        }
        const int hi = (cnt < 31 ? cnt : 31) - 16;
        if (lane < KK && (lane == 0 || lane > hi)) row[lane] = fj;
    }
    __syncthreads();

    // ---- gather: thread t -> output row (t&63), channel quarter (t>>6) ----
    const int rowi = t & 63;
    const int part = t >> 6;
    const int id   = sids[rowi];
    const int ob   = (beta & 1023) * 64 + rowi;

    if (part == 0) {                                // dilated_xyz [B,3,N,K]
        float* o0 = out + (size_t)b * 3 * PLANE + ob;
        o0[0]         = xb[3 * id];
        o0[PLANE]     = xb[3 * id + 1];
        o0[2 * PLANE] = xb[3 * id + 2];
    }

    // dilated_feature [B,64,N,K], channels [16*part, 16*part+16)
    const float4* frow = reinterpret_cast<const float4*>(feat + ((size_t)(b << 12) + id) * 64) + part * 4;
    float* o1 = out + (size_t)BB * 3 * PLANE + (size_t)b * 64 * PLANE
                    + (size_t)(part * 16) * PLANE + ob;
#pragma unroll
    for (int q = 0; q < 4; ++q) {
        const float4 v = frow[q];
        float* oc = o1 + (size_t)(4 * q) * PLANE;
        oc[0]         = v.x;
        oc[PLANE]     = v.y;
        oc[2 * PLANE] = v.z;
        oc[3 * PLANE] = v.w;
    }
}

extern "C" void kernel_launch(void* const* d_in, const int* in_sizes, int n_in,
                              void* d_out, int out_size, void* d_ws, size_t ws_size,
                              hipStream_t stream) {
    const float* xyz  = (const float*)d_in[0];
    const float* feat = (const float*)d_in[1];
    float* out = (float*)d_out;

    char* ws = (char*)d_ws;
    float4* SP = (float4*)(ws);                // 16384*16 = 262144
    int*    SI = (int*)   (ws + 262144);       // 16384*4  = 65536
    int*    CS = (int*)   (ws + 327680);       // 4*401*4  = 6416 (total ~334 KB)

    preprocess  <<<BB,          1024, 0, stream>>>(xyz, SP, SI, CS);
    query_gather<<<BB * NN / 4, 256,  0, stream>>>(xyz, SP, SI, CS, feat, out);
}

// Round 13
// 102.004 us; speedup vs baseline: 1.0503x; 1.0488x over previous
//
#include <hip/hip_runtime.h>

// AnnularDilatedKNN: B=4, N=4096, C=64, SAMPLE=16, DILATED_RATE=2, r^2=256.
// Round 16: round-8 base (BEST, 102.2us, passed 2x; r12 sorted and r15
// sq/SI both regressed ~5us -> reverted) + finer grid: cell 16 -> 8
// (NC=40, 1600 cells). Search box 48x48 -> 40x40 = 0.69x candidates
// (~834 -> ~578/point), cutting query L2 traffic + VALU proportionally.
//  - |dx|<=16 => |dcell|<=2 at cell=8: +/-2-cell x-window, 5 y-rows cover
//    the ball; clamped dup rows harmless (idempotent mask OR).
//  - K2 loop shape BYTE-PATTERN-identical to round-8 (per-row dual-chunk
//    guarded loop, bounds in named scalars, select chain 3->5). No loop
//    restructure (r7/r8/r14 crash pattern), no speculative loads.
//  - Index in SP.w (bitcast), sqj recomputed per candidate (r8 scheme --
//    r15's SI/hit-load variant was SLOWER).
//  - K1: 1024-thread preprocess (passed 4x), hist 1600 cells (2-iter zero),
//    wave-0 scan at 25 cells/lane via LDS re-read loops (no reg arrays).
//  Hit test bit-identical: sq=(x*x+y*y)+z*z, dot=(xi*xj+yi*yj)+zi*zj,
//  d2=(sqi+sqj)-2*dot, contract off.

#define BB 4
#define NN 4096
#define KK 16
#define PLANE (NN * KK)   // 65536
#define NC 40
#define NCELL2 (NC * NC)  // 1600

__device__ __forceinline__ int cell1d(float v)
{
    int c = (int)floorf((v + 160.0f) * 0.125f);
    c = c < 0 ? 0 : c;
    return c > (NC - 1) ? (NC - 1) : c;
}

// ---------- K1: per-batch 2D histogram -> scan -> scatter (1 block/batch) ----------
// 1024 threads; thread t owns points 4t..4t+3 of its batch.
__global__ __launch_bounds__(1024)
void preprocess(const float* __restrict__ xyz, float4* __restrict__ SP,
                int* __restrict__ CS)
{
#pragma clang fp contract(off)
    __shared__ int hist[NCELL2];

    const int b = blockIdx.x;
    const int t = threadIdx.x;
    const float4* xb4 = (const float4*)(xyz + (size_t)b * NN * 3);

    for (int c = t; c < NCELL2; c += 1024) hist[c] = 0;
    __syncthreads();

    // load 4 consecutive points (3 coalesced float4), keep in registers
    const float4 v0 = xb4[3 * t];
    const float4 v1 = xb4[3 * t + 1];
    const float4 v2 = xb4[3 * t + 2];
    const float px0 = v0.x, py0 = v0.y, pz0 = v0.z;
    const float px1 = v0.w, py1 = v1.x, pz1 = v1.y;
    const float px2 = v1.z, py2 = v1.w, pz2 = v2.x;
    const float px3 = v2.y, py3 = v2.z, pz3 = v2.w;
    const int c0 = cell1d(py0) * NC + cell1d(px0);
    const int c1 = cell1d(py1) * NC + cell1d(px1);
    const int c2 = cell1d(py2) * NC + cell1d(px2);
    const int c3 = cell1d(py3) * NC + cell1d(px3);
    atomicAdd(&hist[c0], 1);
    atomicAdd(&hist[c1], 1);
    atomicAdd(&hist[c2], 1);
    atomicAdd(&hist[c3], 1);
    __syncthreads();

    // wave 0 scans the 1600 cells (25 cells/lane, LDS re-read, no reg arrays)
    if (t < 64) {
        const int base = t * 25;                    // 64*25 = 1600 exactly
        int s = 0;
        for (int c = base; c < base + 25; ++c) s += hist[c];
        int x = s;
#pragma unroll
        for (int off = 1; off < 64; off <<= 1) {
            const int u = __shfl_up(x, off, 64);
            if (t >= off) x += u;
        }
        int acc = x - s;                            // exclusive prefix
        int* cs = CS + b * (NCELL2 + 1);
        for (int c = base; c < base + 25; ++c) {
            const int v = hist[c];
            cs[c]   = acc;
            hist[c] = acc;
            acc += v;
        }
        if (t == 0) cs[NCELL2] = NN;
    }
    __syncthreads();

    // scatter from registers; SP.w carries original index (round-8 scheme)
    {
        int slot;
        slot = atomicAdd(&hist[c0], 1);
        SP[(b << 12) + slot] = make_float4(px0, py0, pz0, __int_as_float(4 * t + 0));
        slot = atomicAdd(&hist[c1], 1);
        SP[(b << 12) + slot] = make_float4(px1, py1, pz1, __int_as_float(4 * t + 1));
        slot = atomicAdd(&hist[c2], 1);
        SP[(b << 12) + slot] = make_float4(px2, py2, pz2, __int_as_float(4 * t + 2));
        slot = atomicAdd(&hist[c3], 1);
        SP[(b << 12) + slot] = make_float4(px3, py3, pz3, __int_as_float(4 * t + 3));
    }
}

// ---------- K2: fused grid ball query + gather ----------
// grid: 4096 blocks x 256 threads; block handles 4 consecutive points
// (ORIGINAL order), wave w queries point p0+w via 5 contiguous runs.
__global__ __launch_bounds__(256, 8)
void query_gather(const float* __restrict__ xyz, const float4* __restrict__ SP,
                  const int* __restrict__ CS, const float* __restrict__ feat,
                  float* __restrict__ out)
{
#pragma clang fp contract(off)
    __shared__ unsigned int mask[4][128];   // 4096-bit hit mask per point
    __shared__ int sids[4 * KK];

    const int beta = blockIdx.x;
    const int b    = beta >> 10;
    const int p0   = (beta & 1023) * 4;
    const int t    = threadIdx.x;
    const int lane = t & 63;
    const int wave = t >> 6;

    const float* xb   = xyz + (size_t)b * NN * 3;
    const float4* Sb  = SP + (b << 12);
    const int*    csb = CS + b * (NCELL2 + 1);

    // own point (original order): wave-uniform scalar loads, sq bit-identical
    const int   ip  = p0 + wave;
    const float pix = xb[3 * ip];
    const float piy = xb[3 * ip + 1];
    const float piz = xb[3 * ip + 2];
    const float sqi = (pix * pix + piy * piy) + piz * piz;

    // zero own mask (own-wave use only -> no barrier needed before query)
    unsigned int* m = mask[wave];
    m[2 * lane]     = 0u;
    m[2 * lane + 1] = 0u;

    // ---- query: 5 y-rows, bounds hoisted to named scalars, dual-chunk loop ----
    {
        const int cx = cell1d(pix), cy = cell1d(piy);
        const int xlo = cx > 1 ? cx - 2 : 0;
        const int xhi = cx < NC - 2 ? cx + 2 : NC - 1;
        const int y0 = (cy - 2) < 0 ? 0 : cy - 2;            // dup rows harmless (OR)
        const int y1 = (cy - 1) < 0 ? 0 : cy - 1;
        const int y3 = (cy + 1) > NC - 1 ? NC - 1 : cy + 1;
        const int y4 = (cy + 2) > NC - 1 ? NC - 1 : cy + 2;

        // all 10 bounds issued up-front, independent wave-uniform loads
        const int s0 = csb[y0 * NC + xlo], e0 = csb[y0 * NC + xhi + 1];
        const int s1 = csb[y1 * NC + xlo], e1 = csb[y1 * NC + xhi + 1];
        const int s2 = csb[cy * NC + xlo], e2 = csb[cy * NC + xhi + 1];
        const int s3 = csb[y3 * NC + xlo], e3 = csb[y3 * NC + xhi + 1];
        const int s4 = csb[y4 * NC + xlo], e4 = csb[y4 * NC + xhi + 1];

#pragma unroll
        for (int rr = 0; rr < 5; ++rr) {
            const int s = rr == 0 ? s0 : (rr == 1 ? s1 : (rr == 2 ? s2 : (rr == 3 ? s3 : s4)));
            const int e = rr == 0 ? e0 : (rr == 1 ? e1 : (rr == 2 ? e2 : (rr == 3 ? e3 : e4)));
            for (int v = s + lane; v < e; v += 128) {         // 2 chunks/iter
                const float4 a = Sb[v];
                const int v2   = v + 64;
                const bool h2  = v2 < e;
                float4 c2;
                if (h2) c2 = Sb[v2];                          // guarded, no spec
                const float sqa = (a.x * a.x + a.y * a.y) + a.z * a.z;
                const float da  = (pix * a.x + piy * a.y) + piz * a.z;
                const float d2a = (sqi + sqa) - 2.0f * da;
                if (d2a < 256.0f) {
                    const int j = __float_as_int(a.w);
                    atomicOr(&m[j >> 5], 1u << (j & 31));
                }
                if (h2) {
                    const float sqc = (c2.x * c2.x + c2.y * c2.y) + c2.z * c2.z;
                    const float dc  = (pix * c2.x + piy * c2.y) + piz * c2.z;
                    const float d2c = (sqi + sqc) - 2.0f * dc;
                    if (d2c < 256.0f) {
                        const int j = __float_as_int(c2.w);
                        atomicOr(&m[j >> 5], 1u << (j & 31));
                    }
                }
            }
        }
    }

    // ---- rank extraction: lane l owns indices [64l, 64l+64) (own mask) ----
    {
        const unsigned int lo  = m[2 * lane];
        const unsigned int hiw = m[2 * lane + 1];
        const unsigned long long w = ((unsigned long long)hiw << 32) | lo;
        const int c = __popcll(w);
        int x = c;                                  // inclusive scan of counts
#pragma unroll
        for (int off = 1; off < 64; off <<= 1) {
            const int u = __shfl_up(x, off, 64);
            if (lane >= off) x += u;
        }
        const int cnt  = __shfl(x, 63, 64);         // total hits
        const int base = x - c;                     // hits before this lane

        int fj = 0x7fffffff;                        // global first hit
        if (w) fj = (lane << 6) + __builtin_ctzll(w);
        for (int off = 32; off; off >>= 1) {
            const int o = __shfl_xor(fj, off, 64);
            fj = fj < o ? fj : o;
        }

        int* row = sids + wave * KK;
        if (w && base <= 30 && base + c > 16) {     // lane covers ranks 16..30?
            unsigned long long ww = w;
            int r = base;
            while (ww) {
                if (r > 30) break;
                if (r >= 16) row[r - 15] = (lane << 6) + __builtin_ctzll(ww);
                ww &= ww - 1;
                ++r;
            }
        }
        const int hi = (cnt < 31 ? cnt : 31) - 16;
        if (lane < KK && (lane == 0 || lane > hi)) row[lane] = fj;
    }
    __syncthreads();

    // ---- gather: thread t -> output row (t&63), channel quarter (t>>6) ----
    const int rowi = t & 63;
    const int part = t >> 6;
    const int id   = sids[rowi];
    const int ob   = (beta & 1023) * 64 + rowi;

    if (part == 0) {                                // dilated_xyz [B,3,N,K]
        float* o0 = out + (size_t)b * 3 * PLANE + ob;
        o0[0]         = xb[3 * id];
        o0[PLANE]     = xb[3 * id + 1];
        o0[2 * PLANE] = xb[3 * id + 2];
    }

    // dilated_feature [B,64,N,K], channels [16*part, 16*part+16)
    const float4* frow = reinterpret_cast<const float4*>(feat + ((size_t)(b << 12) + id) * 64) + part * 4;
    float* o1 = out + (size_t)BB * 3 * PLANE + (size_t)b * 64 * PLANE
                    + (size_t)(part * 16) * PLANE + ob;
#pragma unroll
    for (int q = 0; q < 4; ++q) {
        const float4 v = frow[q];
        float* oc = o1 + (size_t)(4 * q) * PLANE;
        oc[0]         = v.x;
        oc[PLANE]     = v.y;
        oc[2 * PLANE] = v.z;
        oc[3 * PLANE] = v.w;
    }
}

extern "C" void kernel_launch(void* const* d_in, const int* in_sizes, int n_in,
                              void* d_out, int out_size, void* d_ws, size_t ws_size,
                              hipStream_t stream) {
    const float* xyz  = (const float*)d_in[0];
    const float* feat = (const float*)d_in[1];
    float* out = (float*)d_out;

    char* ws = (char*)d_ws;
    float4* SP = (float4*)(ws);                // 16384*16 = 262144
    int*    CS = (int*)   (ws + 262144);       // 4*1601*4 = 25616 (total ~288 KB)

    preprocess  <<<BB,          1024, 0, stream>>>(xyz, SP, CS);
    query_gather<<<BB * NN / 4, 256,  0, stream>>>(xyz, SP, CS, feat, out);
}